// Round 2
// baseline (2384.040 us; speedup 1.0000x reference)
//
#include <hip/hip_runtime.h>
#include <hip/hip_bf16.h>
#include <math.h>

#define BATCH 256
#define NEDGE 4096
#define HDIM 256

__device__ __forceinline__ float gelu_f(float x) {
  // jax.nn.gelu approximate=True: 0.5x(1+tanh(sqrt(2/pi)(x+0.044715x^3)))
  float x3 = x * x * x;
  float t = tanhf(0.7978845608028654f * (x + 0.044715f * x3));
  return 0.5f * x * (1.0f + t);
}

// ---------------- GIN aggregation: h = x + scatter_add(x[src] -> dst) ------
// One block per batch graph. agg tile lives in LDS (<=128 KiB), LDS f32 atomics.
template<int NN, int FF>
__global__ __launch_bounds__(256)
void gin_agg_kernel(const float* __restrict__ x,
                    const int* __restrict__ src_base, int src_stride,
                    const int* __restrict__ dst_base, int dst_stride,
                    float* __restrict__ h) {
  constexpr int LPE = FF / 4;     // lanes per edge (float4 granularity)
  constexpr int GRP = 256 / LPE;  // edges processed in parallel
  __shared__ float agg[NN * FF];
  const int b = blockIdx.x;
  const int tid = threadIdx.x;
  float4* agg4 = (float4*)agg;
  for (int i = tid; i < NN * LPE; i += 256) agg4[i] = make_float4(0.f, 0.f, 0.f, 0.f);
  __syncthreads();
  const int lane = tid % LPE;
  const int grp = tid / LPE;
  const float4* x4 = (const float4*)x + (size_t)b * NN * LPE;
  const int* se = src_base + (size_t)b * src_stride;
  const int* de = dst_base + (size_t)b * dst_stride;
  for (int e = grp; e < NEDGE; e += GRP) {
    int s = se[e];
    if (s < 0) continue;          // invalid edge sentinel
    int d = de[e];
    float4 v = x4[s * LPE + lane];
    float* a = &agg[d * FF + lane * 4];
    atomicAdd(a + 0, v.x);
    atomicAdd(a + 1, v.y);
    atomicAdd(a + 2, v.z);
    atomicAdd(a + 3, v.w);
  }
  __syncthreads();
  float4* h4 = (float4*)h + (size_t)b * NN * LPE;
  for (int i = tid; i < NN * LPE; i += 256) {
    float4 xv = x4[i], av = agg4[i];
    h4[i] = make_float4(xv.x + av.x, xv.y + av.y, xv.z + av.z, xv.w + av.w);
  }
}

// ---------------- fp32 tiled GEMM: C[M,256] = (gelu?)(A[M,K] @ W[K,256] + b) -
// 64x64 tile per block, 256 threads, 4x4 micro-tile, K-step 16.
template<bool GELU>
__global__ __launch_bounds__(256)
void gemm_bias_kernel(const float* __restrict__ A, const float* __restrict__ W,
                      const float* __restrict__ bias, float* __restrict__ C,
                      int M, int K) {
  __shared__ float As[64][20];   // padded: inner reads 2-way at worst
  __shared__ float Ws[16][64];
  const int tid = threadIdx.x;
  const int tx = tid & 15, ty = tid >> 4;
  const int rowBase = blockIdx.x * 64;
  const int colBase = blockIdx.y * 64;
  const int lr = tid >> 2;            // A-load row 0..63
  const int lk = (tid & 3) * 4;       // A-load k quad
  const int wk = tid >> 4;            // W-load k 0..15
  const int wc = (tid & 15) * 4;      // W-load col quad
  float acc[4][4] = {};
  for (int k0 = 0; k0 < K; k0 += 16) {
    float4 av = *(const float4*)&A[(size_t)(rowBase + lr) * K + k0 + lk];
    *(float4*)&As[lr][lk] = av;
    float4 wv = *(const float4*)&W[(size_t)(k0 + wk) * 256 + colBase + wc];
    *(float4*)&Ws[wk][wc] = wv;
    __syncthreads();
#pragma unroll
    for (int kk = 0; kk < 16; ++kk) {
      float a0 = As[ty * 4 + 0][kk];
      float a1 = As[ty * 4 + 1][kk];
      float a2 = As[ty * 4 + 2][kk];
      float a3 = As[ty * 4 + 3][kk];
      float4 bv = *(const float4*)&Ws[kk][tx * 4];
      acc[0][0] += a0 * bv.x; acc[0][1] += a0 * bv.y; acc[0][2] += a0 * bv.z; acc[0][3] += a0 * bv.w;
      acc[1][0] += a1 * bv.x; acc[1][1] += a1 * bv.y; acc[1][2] += a1 * bv.z; acc[1][3] += a1 * bv.w;
      acc[2][0] += a2 * bv.x; acc[2][1] += a2 * bv.y; acc[2][2] += a2 * bv.z; acc[2][3] += a2 * bv.w;
      acc[3][0] += a3 * bv.x; acc[3][1] += a3 * bv.y; acc[3][2] += a3 * bv.z; acc[3][3] += a3 * bv.w;
    }
    __syncthreads();
  }
  float4 b4 = *(const float4*)&bias[colBase + tx * 4];
#pragma unroll
  for (int i = 0; i < 4; ++i) {
    float4 o;
    o.x = acc[i][0] + b4.x;
    o.y = acc[i][1] + b4.y;
    o.z = acc[i][2] + b4.z;
    o.w = acc[i][3] + b4.w;
    if (GELU) { o.x = gelu_f(o.x); o.y = gelu_f(o.y); o.z = gelu_f(o.z); o.w = gelu_f(o.w); }
    *(float4*)&C[(size_t)(rowBase + ty * 4 + i) * 256 + colBase + tx * 4] = o;
  }
}

// ---------------- BN stats: two-stage deterministic reduction ---------------
__global__ __launch_bounds__(256)
void bn_partial_kernel(const float* __restrict__ y, int M,
                       double* __restrict__ P1, double* __restrict__ P2) {
  const int c = threadIdx.x;
  double s = 0.0, s2 = 0.0;
  for (int r = blockIdx.x; r < M; r += 256) {
    float v = y[(size_t)r * 256 + c];
    s += (double)v;
    s2 += (double)v * (double)v;
  }
  P1[blockIdx.x * 256 + c] = s;
  P2[blockIdx.x * 256 + c] = s2;
}

// stats layout: [0..255]=mean, [256..511]=rsqrt(var+eps), [512]=1/||pw||
__global__ __launch_bounds__(256)
void bn_finalize_kernel(const double* __restrict__ P1, const double* __restrict__ P2,
                        int M, const float* __restrict__ pw, float* __restrict__ stats) {
  const int c = threadIdx.x;
  double s = 0.0, s2 = 0.0;
  for (int i = 0; i < 256; ++i) { s += P1[i * 256 + c]; s2 += P2[i * 256 + c]; }
  double mean = s / (double)M;
  double var = s2 / (double)M - mean * mean;
  stats[c] = (float)mean;
  stats[256 + c] = (float)(1.0 / sqrt(var + 1e-5));
  float w = pw[c];
  __shared__ float red[256];
  red[c] = w * w;
  __syncthreads();
  for (int off = 128; off; off >>= 1) {
    if (c < off) red[c] += red[c + off];
    __syncthreads();
  }
  if (c == 0) stats[512] = rsqrtf(red[0]);
}

// ---------------- score[row] = dot(gelu(bn(y[row])), pw) / ||pw|| -----------
__global__ __launch_bounds__(256)
void score_kernel(const float* __restrict__ y, const float* __restrict__ stats,
                  const float* __restrict__ gamma, const float* __restrict__ beta,
                  const float* __restrict__ pw, float* __restrict__ scores) {
  const int row = blockIdx.x;
  const int c = threadIdx.x;
  float v = y[(size_t)row * 256 + c];
  float xp = gelu_f((v - stats[c]) * stats[256 + c] * gamma[c] + beta[c]);
  float p = xp * pw[c] * stats[512];
  for (int off = 32; off; off >>= 1) p += __shfl_down(p, off, 64);
  __shared__ float red[4];
  const int lane = c & 63, wid = c >> 6;
  if (lane == 0) red[wid] = p;
  __syncthreads();
  if (c == 0) scores[row] = red[0] + red[1] + red[2] + red[3];
}

// ---------------- top-k pool + readout + edge remap (block per batch) -------
__global__ __launch_bounds__(256)
void pool_kernel(const float* __restrict__ y, const float* __restrict__ scores,
                 const float* __restrict__ stats, const float* __restrict__ gamma,
                 const float* __restrict__ beta,
                 const int* __restrict__ src_in, int src_stride,
                 const int* __restrict__ dst_in, int dst_stride,
                 int* __restrict__ src_out, int* __restrict__ dst_out,
                 float* __restrict__ xnext, float* __restrict__ total,
                 int n, int k, int accumulate) {
  const int b = blockIdx.x;
  const int tid = threadIdx.x;
  __shared__ float s_sc[256];
  __shared__ float s_tv[256];
  __shared__ int s_map[256];
  if (tid < n) {
    float si = scores[b * n + tid];
    s_sc[tid] = si;
    s_tv[tid] = tanhf(si);
  }
  __syncthreads();
  if (tid < n) {
    // rank = #nodes strictly ahead (ties: lower index first, matches lax.top_k)
    float si = s_sc[tid];
    int r = 0;
    for (int j = 0; j < n; ++j) {
      float sj = s_sc[j];
      r += (sj > si) || (sj == si && j < tid);
    }
    s_map[tid] = (r < k) ? r : -1;
  }
  __syncthreads();
  // gather selected rows (recompute gelu(bn(y)) on the fly), readout max/mean
  const int c = tid;
  const float mean = stats[c], inv = stats[256 + c], ga = gamma[c], be = beta[c];
  float mx = -INFINITY, sm = 0.f;
  for (int i = 0; i < n; ++i) {
    int r = s_map[i];
    if (r < 0) continue;
    float v = y[((size_t)b * n + i) * 256 + c];
    float xp = gelu_f((v - mean) * inv * ga + be);
    float o = xp * s_tv[i];
    xnext[((size_t)b * k + r) * 256 + c] = o;
    mx = fmaxf(mx, o);
    sm += o;
  }
  float* tb = total + b * 512;
  float aval = sm / (float)k;
  if (accumulate) { tb[c] += mx; tb[256 + c] += aval; }
  else            { tb[c] = mx;  tb[256 + c] = aval; }
  // edge remap for next layer (ping-pong buffers: in != out)
  const int* se = src_in + (size_t)b * src_stride;
  const int* de = dst_in + (size_t)b * dst_stride;
  int* so = src_out + (size_t)b * NEDGE;
  int* dq = dst_out + (size_t)b * NEDGE;
  for (int e = tid; e < NEDGE; e += 256) {
    int s = se[e], d = de[e];
    int ns = -1, nd = -1;
    if (s >= 0 && d >= 0) {
      ns = s_map[s];
      nd = s_map[d];
      if (ns < 0 || nd < 0) { ns = -1; nd = -1; }
    }
    so[e] = ns;
    dq[e] = nd;
  }
}

// ---------------- out = total @ Wlin + blin ---------------------------------
__global__ __launch_bounds__(256)
void final_linear_kernel(const float* __restrict__ total, const float* __restrict__ Wlin,
                         const float* __restrict__ blin, float* __restrict__ out) {
  const int b = blockIdx.x, o = threadIdx.x;
  __shared__ float tl[512];
  tl[o] = total[b * 512 + o];
  tl[256 + o] = total[b * 512 + 256 + o];
  __syncthreads();
  float acc = blin[o];
  for (int cc = 0; cc < 512; ++cc) acc += tl[cc] * Wlin[cc * 256 + o];
  out[b * 256 + o] = acc;
}

// ---------------- per-layer driver ------------------------------------------
template<int NN, int FF>
static void run_layer(const float* xin,
                      const int* src_in, int sstr, const int* dst_in, int dstr,
                      int* src_out, int* dst_out,
                      const float* const* P,  // W1,b1,W2,b2,gamma,beta,pw
                      float* R1, float* R2, float* scores, float* stats,
                      double* P1, double* P2,
                      float* xnext, float* total, int accumulate,
                      hipStream_t stream) {
  constexpr int M = BATCH * NN;
  gin_agg_kernel<NN, FF><<<BATCH, 256, 0, stream>>>(xin, src_in, sstr, dst_in, dstr, R1);
  gemm_bias_kernel<true><<<dim3(M / 64, 4), 256, 0, stream>>>(R1, P[0], P[1], R2, M, FF);
  gemm_bias_kernel<false><<<dim3(M / 64, 4), 256, 0, stream>>>(R2, P[2], P[3], R1, M, 256);
  bn_partial_kernel<<<256, 256, 0, stream>>>(R1, M, P1, P2);
  bn_finalize_kernel<<<1, 256, 0, stream>>>(P1, P2, M, P[6], stats);
  score_kernel<<<M, 256, 0, stream>>>(R1, stats, P[4], P[5], P[6], scores);
  pool_kernel<<<BATCH, 256, 0, stream>>>(R1, scores, stats, P[4], P[5],
                                         src_in, sstr, dst_in, dstr, src_out, dst_out,
                                         xnext, total, NN, NN / 2, accumulate);
}

extern "C" void kernel_launch(void* const* d_in, const int* in_sizes, int n_in,
                              void* d_out, int out_size, void* d_ws, size_t ws_size,
                              hipStream_t stream) {
  (void)in_sizes; (void)n_in; (void)out_size; (void)ws_size;
  const float* x0 = (const float*)d_in[0];
  const int* ei = (const int*)d_in[1];
  const float* Wlin = (const float*)d_in[30];
  const float* blin = (const float*)d_in[31];
  const float* Lp[4][7];
  for (int l = 0; l < 4; ++l)
    for (int j = 0; j < 7; ++j)
      Lp[l][j] = (const float*)d_in[2 + l * 7 + j];

  char* ws = (char*)d_ws;
  size_t off = 0;
  auto alloc = [&](size_t bytes) -> void* {
    void* p = ws + off;
    off += (bytes + 255) & ~(size_t)255;
    return p;
  };
  float* xA = (float*)alloc((size_t)BATCH * 128 * 256 * 4);      // pooled x (max layer-1 out)
  float* R1 = (float*)alloc((size_t)BATCH * 256 * 256 * 4);      // h, then y
  float* R2 = (float*)alloc((size_t)BATCH * 256 * 256 * 4);      // t
  float* scores = (float*)alloc((size_t)BATCH * 256 * 4);
  float* stats = (float*)alloc(4096);
  double* P1 = (double*)alloc((size_t)256 * 256 * 8);
  double* P2 = (double*)alloc((size_t)256 * 256 * 8);
  int* es0 = (int*)alloc((size_t)BATCH * NEDGE * 4);
  int* ed0 = (int*)alloc((size_t)BATCH * NEDGE * 4);
  int* es1 = (int*)alloc((size_t)BATCH * NEDGE * 4);
  int* ed1 = (int*)alloc((size_t)BATCH * NEDGE * 4);
  float* total = (float*)alloc((size_t)BATCH * 512 * 4);

  // layer 1: n=256, F=128; edges straight from edge_index (B,2,E)
  run_layer<256, 128>(x0, ei, 2 * NEDGE, ei + NEDGE, 2 * NEDGE, es0, ed0,
                      Lp[0], R1, R2, scores, stats, P1, P2, xA, total, 0, stream);
  // layer 2: n=128, F=256
  run_layer<128, 256>(xA, es0, NEDGE, ed0, NEDGE, es1, ed1,
                      Lp[1], R1, R2, scores, stats, P1, P2, xA, total, 1, stream);
  // layer 3: n=64, F=256
  run_layer<64, 256>(xA, es1, NEDGE, ed1, NEDGE, es0, ed0,
                     Lp[2], R1, R2, scores, stats, P1, P2, xA, total, 1, stream);
  // layer 4: n=32, F=256
  run_layer<32, 256>(xA, es0, NEDGE, ed0, NEDGE, es1, ed1,
                     Lp[3], R1, R2, scores, stats, P1, P2, xA, total, 1, stream);

  final_linear_kernel<<<BATCH, 256, 0, stream>>>(total, Wlin, blin, (float*)d_out);
}

// Round 7
// 1117.361 us; speedup vs baseline: 2.1336x; 2.1336x over previous
//
#include <hip/hip_runtime.h>
#include <hip/hip_bf16.h>
#include <math.h>

#define BATCH 256
#define NEDGE 4096
#define HDIM 256

typedef __attribute__((ext_vector_type(8))) short short8v;   // 8 bf16 = 4 VGPR
typedef __attribute__((ext_vector_type(4))) float float4v;

__device__ __forceinline__ float gelu_f(float x) {
  // jax.nn.gelu approximate=True: 0.5x(1+tanh(sqrt(2/pi)(x+0.044715x^3)))
  float x3 = x * x * x;
  float t = tanhf(0.7978845608028654f * (x + 0.044715f * x3));
  return 0.5f * x * (1.0f + t);
}

__device__ __forceinline__ void split_bf16(float v, __hip_bfloat16& hi, __hip_bfloat16& lo) {
  hi = __float2bfloat16(v);
  lo = __float2bfloat16(v - __bfloat162float(hi));
}

// ---------------- GIN aggregation: h = x + scatter_add(x[src] -> dst) ------
// Grid (BATCH, FF/32). Per-batch CSR in LDS, register accumulation.
// Emits h as split-bf16 (hi, lo) feeding the MFMA GEMM.
template<int NN, int FF>
__global__ __launch_bounds__(256)
void gin_agg_kernel(const float* __restrict__ x,
                    const int* __restrict__ src_base, int src_stride,
                    const int* __restrict__ dst_base, int dst_stride,
                    __hip_bfloat16* __restrict__ Hhi,
                    __hip_bfloat16* __restrict__ Hlo) {
  constexpr int FCH = 32;            // feature floats per block
  constexpr int LPE = FCH / 4;       // 8 lanes per row-slice
  constexpr int GRP = 256 / LPE;     // 32 rows accumulated in parallel
  constexpr int F4 = FF / 4;
  __shared__ int s_cnt[NN];          // counts, then fill cursor
  __shared__ int s_rs[NN + 1];       // CSR row starts
  __shared__ int s_csr[NEDGE];       // src ids grouped by dst
  const int b = blockIdx.x;
  const int chunk = blockIdx.y;
  const int tid = threadIdx.x;
  const int* se = src_base + (size_t)b * src_stride;
  const int* de = dst_base + (size_t)b * dst_stride;
  if (tid < NN) s_cnt[tid] = 0;
  __syncthreads();
  for (int e = tid; e < NEDGE; e += 256) {
    int s = se[e];
    if (s >= 0) atomicAdd(&s_cnt[de[e]], 1);
  }
  __syncthreads();
  if (tid < NN) s_rs[tid] = s_cnt[tid];
  __syncthreads();
  for (int off = 1; off < NN; off <<= 1) {
    int add = 0;
    if (tid < NN && tid >= off) add = s_rs[tid - off];
    __syncthreads();
    if (tid < NN) s_rs[tid] += add;
    __syncthreads();
  }
  int incl = (tid < NN) ? s_rs[tid] : 0;
  __syncthreads();
  if (tid < NN) s_rs[tid + 1] = incl;
  if (tid == 0) s_rs[0] = 0;
  if (tid < NN) s_cnt[tid] = 0;
  __syncthreads();
  for (int e = tid; e < NEDGE; e += 256) {
    int s = se[e];
    if (s >= 0) {
      int d = de[e];
      int p = s_rs[d] + atomicAdd(&s_cnt[d], 1);
      s_csr[p] = s;
    }
  }
  __syncthreads();
  const int lane = tid & (LPE - 1);
  const int grp = tid / LPE;
  const int cb = chunk * LPE;        // float4 column base
  const float4* x4 = (const float4*)x + (size_t)b * NN * F4;
  for (int d = grp; d < NN; d += GRP) {
    int j0 = s_rs[d], j1 = s_rs[d + 1];
    float4 acc = x4[(size_t)d * F4 + cb + lane];
    for (int j = j0; j < j1; ++j) {
      int s = s_csr[j];
      float4 xv = x4[(size_t)s * F4 + cb + lane];
      acc.x += xv.x; acc.y += xv.y; acc.z += xv.z; acc.w += xv.w;
    }
    float av[4] = {acc.x, acc.y, acc.z, acc.w};
    union { __hip_bfloat16 h[4]; uint2 u; } hv, lv;   // aligned views
#pragma unroll
    for (int j = 0; j < 4; ++j) split_bf16(av[j], hv.h[j], lv.h[j]);
    size_t eo = ((size_t)b * NN + d) * FF + (cb + lane) * 4;
    *(uint2*)&Hhi[eo] = hv.u;
    *(uint2*)&Hlo[eo] = lv.u;
  }
}

// ---------------- weight transpose + split: W[K][256] -> Wt{hi,lo}[256][K] --
template<int K>
__global__ __launch_bounds__(256)
void wsplit_kernel(const float* __restrict__ W,
                   __hip_bfloat16* __restrict__ Whi, __hip_bfloat16* __restrict__ Wlo) {
  int idx = blockIdx.x * 256 + threadIdx.x;   // over 256*K outputs
  int c = idx / K, k = idx % K;               // K pow2, compile-time
  float w = W[(size_t)k * 256 + c];
  __hip_bfloat16 hi, lo;
  split_bf16(w, hi, lo);
  Whi[idx] = hi;   // idx == c*K + k
  Wlo[idx] = lo;
}

// ---------------- MFMA GEMM: C[M,256] = A[M,K] @ W[K,256] + b ---------------
// Split-bf16 3-product emulation (~fp32 precision). No LDS: fragments load
// direct from global; W^T-split is L2-resident. Block 256 thr = 4 waves (2x2),
// wave tile 64x64 = 4x4 frags of 16x16x32. MODE 0: f32 out; 1: gelu+split out.
template<int K, int MODE>
__global__ __launch_bounds__(256)
void mfma_gemm_kernel(const __hip_bfloat16* __restrict__ Ahi,
                      const __hip_bfloat16* __restrict__ Alo,
                      const __hip_bfloat16* __restrict__ Bhi,  // [256][K] = W^T
                      const __hip_bfloat16* __restrict__ Blo,
                      const float* __restrict__ bias,
                      float* __restrict__ Cf,
                      __hip_bfloat16* __restrict__ Chi,
                      __hip_bfloat16* __restrict__ Clo) {
  const int tid = threadIdx.x;
  const int wid = tid >> 6, lane = tid & 63;
  const int wr = wid >> 1, wc = wid & 1;
  const int lr = lane & 15, lg = lane >> 4;
  const int rowBase = blockIdx.x * 128 + wr * 64;
  const int colBase = blockIdx.y * 128 + wc * 64;
  float4v acc[4][4];
#pragma unroll
  for (int m = 0; m < 4; ++m)
#pragma unroll
    for (int n = 0; n < 4; ++n) acc[m][n] = (float4v){0.f, 0.f, 0.f, 0.f};
#pragma unroll 2
  for (int k0 = 0; k0 < K; k0 += 32) {
    short8v ah[4], al[4], bh[4], bl[4];
#pragma unroll
    for (int m = 0; m < 4; ++m) {
      size_t off = (size_t)(rowBase + m * 16 + lr) * K + k0 + lg * 8;
      ah[m] = *(const short8v*)(Ahi + off);
      al[m] = *(const short8v*)(Alo + off);
    }
#pragma unroll
    for (int n = 0; n < 4; ++n) {
      size_t off = (size_t)(colBase + n * 16 + lr) * K + k0 + lg * 8;
      bh[n] = *(const short8v*)(Bhi + off);
      bl[n] = *(const short8v*)(Blo + off);
    }
#pragma unroll
    for (int m = 0; m < 4; ++m)
#pragma unroll
      for (int n = 0; n < 4; ++n) {
        acc[m][n] = __builtin_amdgcn_mfma_f32_16x16x32_bf16(ah[m], bh[n], acc[m][n], 0, 0, 0);
        acc[m][n] = __builtin_amdgcn_mfma_f32_16x16x32_bf16(al[m], bh[n], acc[m][n], 0, 0, 0);
        acc[m][n] = __builtin_amdgcn_mfma_f32_16x16x32_bf16(ah[m], bl[n], acc[m][n], 0, 0, 0);
      }
  }
  // epilogue: C/D frag map (m89-verified): col = lane&15, row = (lane>>4)*4 + i
#pragma unroll
  for (int n = 0; n < 4; ++n) {
    const int col = colBase + n * 16 + lr;
    const float bv = bias[col];
#pragma unroll
    for (int m = 0; m < 4; ++m) {
      const int row0 = rowBase + m * 16 + lg * 4;
#pragma unroll
      for (int i = 0; i < 4; ++i) {
        float o = acc[m][n][i] + bv;
        if (MODE == 1) {
          o = gelu_f(o);
          __hip_bfloat16 hi, lo;
          split_bf16(o, hi, lo);
          Chi[(size_t)(row0 + i) * 256 + col] = hi;
          Clo[(size_t)(row0 + i) * 256 + col] = lo;
        } else {
          Cf[(size_t)(row0 + i) * 256 + col] = o;
        }
      }
    }
  }
}

// ---------------- BN stats: two-stage deterministic reduction ---------------
#define BN_PBLKS 1024
__global__ __launch_bounds__(256)
void bn_partial_kernel(const float* __restrict__ y, int M,
                       double* __restrict__ P1, double* __restrict__ P2) {
  const int c = threadIdx.x;
  double s = 0.0, s2 = 0.0;
  for (int r = blockIdx.x; r < M; r += BN_PBLKS) {
    float v = y[(size_t)r * 256 + c];
    s += (double)v;
    s2 += (double)v * (double)v;
  }
  P1[blockIdx.x * 256 + c] = s;
  P2[blockIdx.x * 256 + c] = s2;
}

// stats layout: [0..255]=mean, [256..511]=rsqrt(var+eps), [512]=1/||pw||
__global__ __launch_bounds__(256)
void bn_finalize_kernel(const double* __restrict__ P1, const double* __restrict__ P2,
                        int M, const float* __restrict__ pw, float* __restrict__ stats) {
  const int c = threadIdx.x;
  double s = 0.0, s2 = 0.0;
  for (int i = 0; i < BN_PBLKS; ++i) { s += P1[i * 256 + c]; s2 += P2[i * 256 + c]; }
  double mean = s / (double)M;
  double var = s2 / (double)M - mean * mean;
  stats[c] = (float)mean;
  stats[256 + c] = (float)(1.0 / sqrt(var + 1e-5));
  float w = pw[c];
  __shared__ float red[256];
  red[c] = w * w;
  __syncthreads();
  for (int off = 128; off; off >>= 1) {
    if (c < off) red[c] += red[c + off];
    __syncthreads();
  }
  if (c == 0) stats[512] = rsqrtf(red[0]);
}

// ---------------- score[row] = dot(gelu(bn(y[row])), pw) / ||pw|| -----------
#define SC_ROWS 16
__global__ __launch_bounds__(256)
void score_kernel(const float* __restrict__ y, const float* __restrict__ stats,
                  const float* __restrict__ gamma, const float* __restrict__ beta,
                  const float* __restrict__ pw, float* __restrict__ scores) {
  const int tid = threadIdx.x;
  const int lane = tid & 63, wid = tid >> 6;
  const float4 mean = ((const float4*)stats)[lane];
  const float4 inv = ((const float4*)(stats + 256))[lane];
  const float4 ga = ((const float4*)gamma)[lane];
  const float4 be = ((const float4*)beta)[lane];
  const float4 w = ((const float4*)pw)[lane];
  const float invn = stats[512];
#pragma unroll
  for (int i = 0; i < SC_ROWS / 4; ++i) {
    const int row = blockIdx.x * SC_ROWS + wid + 4 * i;
    float4 v = ((const float4*)y)[(size_t)row * 64 + lane];
    float p = gelu_f((v.x - mean.x) * inv.x * ga.x + be.x) * w.x
            + gelu_f((v.y - mean.y) * inv.y * ga.y + be.y) * w.y
            + gelu_f((v.z - mean.z) * inv.z * ga.z + be.z) * w.z
            + gelu_f((v.w - mean.w) * inv.w * ga.w + be.w) * w.w;
    p *= invn;
#pragma unroll
    for (int off = 32; off; off >>= 1) p += __shfl_xor(p, off, 64);
    if (lane == 0) scores[row] = p;
  }
}

// ---------------- top-k pool + readout + edge remap (block per batch) -------
__global__ __launch_bounds__(256)
void pool_kernel(const float* __restrict__ y, const float* __restrict__ scores,
                 const float* __restrict__ stats, const float* __restrict__ gamma,
                 const float* __restrict__ beta,
                 const int* __restrict__ src_in, int src_stride,
                 const int* __restrict__ dst_in, int dst_stride,
                 int* __restrict__ src_out, int* __restrict__ dst_out,
                 float* __restrict__ xnext, float* __restrict__ total,
                 int n, int k, int accumulate) {
  const int b = blockIdx.x;
  const int tid = threadIdx.x;
  __shared__ float s_sc[256];
  __shared__ float s_tv[256];
  __shared__ int s_map[256];
  if (tid < n) {
    float si = scores[b * n + tid];
    s_sc[tid] = si;
    s_tv[tid] = tanhf(si);
  }
  __syncthreads();
  if (tid < n) {
    // rank = #nodes strictly ahead (ties: lower index first, matches lax.top_k)
    float si = s_sc[tid];
    int r = 0;
    for (int j = 0; j < n; ++j) {
      float sj = s_sc[j];
      r += (sj > si) || (sj == si && j < tid);
    }
    s_map[tid] = (r < k) ? r : -1;
  }
  __syncthreads();
  const int c = tid;
  const float mean = stats[c], inv = stats[256 + c], ga = gamma[c], be = beta[c];
  float mx = -INFINITY, sm = 0.f;
  for (int i = 0; i < n; ++i) {
    int r = s_map[i];
    if (r < 0) continue;
    float v = y[((size_t)b * n + i) * 256 + c];
    float xp = gelu_f((v - mean) * inv * ga + be);
    float o = xp * s_tv[i];
    xnext[((size_t)b * k + r) * 256 + c] = o;
    mx = fmaxf(mx, o);
    sm += o;
  }
  float* tb = total + b * 512;
  float aval = sm / (float)k;
  if (accumulate) { tb[c] += mx; tb[256 + c] += aval; }
  else            { tb[c] = mx;  tb[256 + c] = aval; }
  const int* se = src_in + (size_t)b * src_stride;
  const int* de = dst_in + (size_t)b * dst_stride;
  int* so = src_out + (size_t)b * NEDGE;
  int* dq = dst_out + (size_t)b * NEDGE;
  for (int e = tid; e < NEDGE; e += 256) {
    int s = se[e], d = de[e];
    int ns = -1, nd = -1;
    if (s >= 0 && d >= 0) {
      ns = s_map[s];
      nd = s_map[d];
      if (ns < 0 || nd < 0) { ns = -1; nd = -1; }
    }
    so[e] = ns;
    dq[e] = nd;
  }
}

// ---------------- out = total @ Wlin + blin ---------------------------------
__global__ __launch_bounds__(256)
void final_linear_kernel(const float* __restrict__ total, const float* __restrict__ Wlin,
                         const float* __restrict__ blin, float* __restrict__ out) {
  const int b = blockIdx.x, o = threadIdx.x;
  __shared__ float tl[512];
  tl[o] = total[b * 512 + o];
  tl[256 + o] = total[b * 512 + 256 + o];
  __syncthreads();
  float acc = blin[o];
  for (int cc = 0; cc < 512; ++cc) acc += tl[cc] * Wlin[cc * 256 + o];
  out[b * 256 + o] = acc;
}

// ---------------- per-layer driver ------------------------------------------
template<int NN, int FF>
static void run_layer(const float* xin,
                      const int* src_in, int sstr, const int* dst_in, int dstr,
                      int* src_out, int* dst_out,
                      const float* const* P,  // W1,b1,W2,b2,gamma,beta,pw
                      __hip_bfloat16* Ahi, __hip_bfloat16* Alo,
                      __hip_bfloat16* Thi, __hip_bfloat16* Tlo,
                      __hip_bfloat16* W1hi, __hip_bfloat16* W1lo,
                      __hip_bfloat16* W2hi, __hip_bfloat16* W2lo,
                      float* y, float* scores, float* stats,
                      double* P1, double* P2,
                      float* xnext, float* total, int accumulate,
                      hipStream_t stream) {
  constexpr int M = BATCH * NN;
  gin_agg_kernel<NN, FF><<<dim3(BATCH, FF / 32), 256, 0, stream>>>(
      xin, src_in, sstr, dst_in, dstr, Ahi, Alo);
  wsplit_kernel<FF><<<FF, 256, 0, stream>>>(P[0], W1hi, W1lo);
  wsplit_kernel<256><<<256, 256, 0, stream>>>(P[2], W2hi, W2lo);
  mfma_gemm_kernel<FF, 1><<<dim3(M / 128, 2), 256, 0, stream>>>(
      Ahi, Alo, W1hi, W1lo, P[1], nullptr, Thi, Tlo);
  mfma_gemm_kernel<256, 0><<<dim3(M / 128, 2), 256, 0, stream>>>(
      Thi, Tlo, W2hi, W2lo, P[3], y, nullptr, nullptr);
  bn_partial_kernel<<<BN_PBLKS, 256, 0, stream>>>(y, M, P1, P2);
  bn_finalize_kernel<<<1, 256, 0, stream>>>(P1, P2, M, P[6], stats);
  score_kernel<<<M / SC_ROWS, 256, 0, stream>>>(y, stats, P[4], P[5], P[6], scores);
  pool_kernel<<<BATCH, 256, 0, stream>>>(y, scores, stats, P[4], P[5],
                                         src_in, sstr, dst_in, dstr, src_out, dst_out,
                                         xnext, total, NN, NN / 2, accumulate);
}

extern "C" void kernel_launch(void* const* d_in, const int* in_sizes, int n_in,
                              void* d_out, int out_size, void* d_ws, size_t ws_size,
                              hipStream_t stream) {
  (void)in_sizes; (void)n_in; (void)out_size; (void)ws_size;
  const float* x0 = (const float*)d_in[0];
  const int* ei = (const int*)d_in[1];
  const float* Wlin = (const float*)d_in[30];
  const float* blin = (const float*)d_in[31];
  const float* Lp[4][7];
  for (int l = 0; l < 4; ++l)
    for (int j = 0; j < 7; ++j)
      Lp[l][j] = (const float*)d_in[2 + l * 7 + j];

  char* ws = (char*)d_ws;
  size_t off = 0;
  auto alloc = [&](size_t bytes) -> void* {
    void* p = ws + off;
    off += (bytes + 255) & ~(size_t)255;
    return p;
  };
  float* xA = (float*)alloc((size_t)BATCH * 128 * 256 * 4);        // pooled x
  float* y = (float*)alloc((size_t)BATCH * 256 * 256 * 4);         // gemm2 out
  __hip_bfloat16* Ahi = (__hip_bfloat16*)alloc((size_t)8388608 * 2);
  __hip_bfloat16* Alo = (__hip_bfloat16*)alloc((size_t)8388608 * 2);
  __hip_bfloat16* Thi = (__hip_bfloat16*)alloc((size_t)BATCH * 256 * 256 * 2);
  __hip_bfloat16* Tlo = (__hip_bfloat16*)alloc((size_t)BATCH * 256 * 256 * 2);
  __hip_bfloat16* W1hi = (__hip_bfloat16*)alloc((size_t)256 * 256 * 2);
  __hip_bfloat16* W1lo = (__hip_bfloat16*)alloc((size_t)256 * 256 * 2);
  __hip_bfloat16* W2hi = (__hip_bfloat16*)alloc((size_t)256 * 256 * 2);
  __hip_bfloat16* W2lo = (__hip_bfloat16*)alloc((size_t)256 * 256 * 2);
  float* scores = (float*)alloc((size_t)BATCH * 256 * 4);
  float* stats = (float*)alloc(4096);
  double* P1 = (double*)alloc((size_t)BN_PBLKS * 256 * 8);
  double* P2 = (double*)alloc((size_t)BN_PBLKS * 256 * 8);
  int* es0 = (int*)alloc((size_t)BATCH * NEDGE * 4);
  int* ed0 = (int*)alloc((size_t)BATCH * NEDGE * 4);
  int* es1 = (int*)alloc((size_t)BATCH * NEDGE * 4);
  int* ed1 = (int*)alloc((size_t)BATCH * NEDGE * 4);
  float* total = (float*)alloc((size_t)BATCH * 512 * 4);

  // layer 1: n=256, F=128; edges straight from edge_index (B,2,E)
  run_layer<256, 128>(x0, ei, 2 * NEDGE, ei + NEDGE, 2 * NEDGE, es0, ed0,
                      Lp[0], Ahi, Alo, Thi, Tlo, W1hi, W1lo, W2hi, W2lo,
                      y, scores, stats, P1, P2, xA, total, 0, stream);
  // layer 2: n=128, F=256
  run_layer<128, 256>(xA, es0, NEDGE, ed0, NEDGE, es1, ed1,
                      Lp[1], Ahi, Alo, Thi, Tlo, W1hi, W1lo, W2hi, W2lo,
                      y, scores, stats, P1, P2, xA, total, 1, stream);
  // layer 3: n=64, F=256
  run_layer<64, 256>(xA, es1, NEDGE, ed1, NEDGE, es0, ed0,
                     Lp[2], Ahi, Alo, Thi, Tlo, W1hi, W1lo, W2hi, W2lo,
                     y, scores, stats, P1, P2, xA, total, 1, stream);
  // layer 4: n=32, F=256
  run_layer<32, 256>(xA, es0, NEDGE, ed0, NEDGE, es1, ed1,
                     Lp[3], Ahi, Alo, Thi, Tlo, W1hi, W1lo, W2hi, W2lo,
                     y, scores, stats, P1, P2, xA, total, 1, stream);

  final_linear_kernel<<<BATCH, 256, 0, stream>>>(total, Wlin, blin, (float*)d_out);
}